// Round 10
// baseline (171.228 us; speedup 1.0000x reference)
//
#include <hip/hip_runtime.h>
#include <stdint.h>

// Problem: N=131072, D=128, W=16, R=5
//   logit[n,r] = e1[n]^T C_r e2[n],  C_r = sum_w weight[w,r] * M_w
//   out[0] = -mean(log_softmax(logit)[n, rels[n]]),  out[1..N] = expected rating
//
// R18: af double-buffer software pipeline + split MFMA chains.
//   R16/R17 invariance (55 vs 54us, different VMEM structure) isolates the
//   wall to the LDS->MFMA->contract core. VGPR_Count=64 is the tell: ONE
//   af buffer -> r+1's ds_reads can't issue until r's MFMAs drain -> each
//   r-step serializes ~120cyc LDS latency + MFMA dep chain; DS floor is
//   13-17us but wall is 54. Fix:
//   - afA/afB named buffers, r fully unrolled (rule #20): PREF(r+1) issues
//     BEFORE COMP(r) -> LDS latency hides under MFMA; compiler can emit
//     partial lgkmcnt waits.
//   - accumulator chains split (k4 01 -> accA, 23 -> accB, summed in the
//     contract): chain depth 4->2, 8 independent chains/wave.
//   VGPR ~118 < 128 cap. Tells: VGPR 105-125 (dbuf materialized),
//   WRITE ~536KB (no spill), conflicts ~2.6M unchanged.

#define NTOT 131072
#define DDIM 128
#define WBAS 16
#define RCLS 5
#define ROWS 32                  // rows per wave
#define WAVES 16                 // waves per block
#define RPB  (WAVES * ROWS)      // 512 rows per block
#define GRID2 (NTOT / RPB)       // 256 blocks
#define NTILE2 (NTOT / ROWS)     // 4096 wave-tiles

typedef __attribute__((ext_vector_type(8))) short bf16x8;
typedef __attribute__((ext_vector_type(4))) float f32x4;

__device__ __forceinline__ unsigned short f2bf(float x) {
    union { float f; unsigned u; } v; v.f = x;
    unsigned u = v.u + 0x7FFFu + ((v.u >> 16) & 1u);
    return (unsigned short)(u >> 16);
}

__device__ __forceinline__ ushort4 f2bf4(float4 v) {
    return make_ushort4(f2bf(v.x), f2bf(v.y), f2bf(v.z), f2bf(v.w));
}

// ---- prep: coalesced read (lanes along e), LDS transpose, bf16 ----
// grid = 80 blocks: r = bx>>4 (5), d-band d0 = (bx&15)*8 (16)
__global__ __launch_bounds__(256) void prep_kernel(
    const float* __restrict__ rel_embeds,    // [W][d][e]
    const float* __restrict__ wsc,           // [W][R]
    unsigned short* __restrict__ Cth)        // [R][e][d] bf16
{
    __shared__ float tile[8][129];
    const int bx = blockIdx.x;
    const int r  = bx >> 4;
    const int d0 = (bx & 15) << 3;
    const int t  = threadIdx.x;

    const int e  = t & 127;     // lanes consecutive in e -> coalesced reads
    const int dl = t >> 7;      // 0..1

    float acc[4] = {0.f, 0.f, 0.f, 0.f};
    for (int w = 0; w < WBAS; ++w) {
        float s = wsc[w * RCLS + r];
#pragma unroll
        for (int dd = 0; dd < 4; ++dd)
            acc[dd] += s * rel_embeds[w * 16384 + (d0 + dd * 2 + dl) * 128 + e];
    }
#pragma unroll
    for (int dd = 0; dd < 4; ++dd) tile[dd * 2 + dl][e] = acc[dd];
    __syncthreads();

    if (t < 128) {          // thread t -> output column e=t, all 8 d of the band
        unsigned short h[8];
#pragma unroll
        for (int j = 0; j < 8; ++j) h[j] = f2bf(tile[j][t]);
        size_t base = (size_t)r * 16384 + (size_t)t * 128 + d0;   // 16B aligned
        *(ushort4*)(Cth + base)     = make_ushort4(h[0], h[1], h[2], h[3]);
        *(ushort4*)(Cth + base + 4) = make_ushort4(h[4], h[5], h[6], h[7]);
    }
}

// prefetch r-plane rr into named buffer (compile-time rr -> static offsets)
#define PREF(buf, rr) do {                                                    \
    _Pragma("unroll")                                                         \
    for (int k4 = 0; k4 < 4; ++k4)                                            \
        buf[k4] = *(const bf16x8*)(rb + (rr) * 32768 + ((q * 16 + k4 * 64) ^ sw)); \
} while (0)

// compute r-plane rr from named buffer: 4 independent 2-deep MFMA chains
#define COMP(buf, rr) do {                                                    \
    f32x4 aa0 = {0.f,0.f,0.f,0.f}, ab0 = {0.f,0.f,0.f,0.f};                   \
    f32x4 aa1 = {0.f,0.f,0.f,0.f}, ab1 = {0.f,0.f,0.f,0.f};                   \
    aa0 = __builtin_amdgcn_mfma_f32_16x16x32_bf16(buf[0], bfr[0][0], aa0, 0, 0, 0); \
    aa1 = __builtin_amdgcn_mfma_f32_16x16x32_bf16(buf[0], bfr[1][0], aa1, 0, 0, 0); \
    ab0 = __builtin_amdgcn_mfma_f32_16x16x32_bf16(buf[2], bfr[0][2], ab0, 0, 0, 0); \
    ab1 = __builtin_amdgcn_mfma_f32_16x16x32_bf16(buf[2], bfr[1][2], ab1, 0, 0, 0); \
    aa0 = __builtin_amdgcn_mfma_f32_16x16x32_bf16(buf[1], bfr[0][1], aa0, 0, 0, 0); \
    aa1 = __builtin_amdgcn_mfma_f32_16x16x32_bf16(buf[1], bfr[1][1], aa1, 0, 0, 0); \
    ab0 = __builtin_amdgcn_mfma_f32_16x16x32_bf16(buf[3], bfr[0][3], ab0, 0, 0, 0); \
    ab1 = __builtin_amdgcn_mfma_f32_16x16x32_bf16(buf[3], bfr[1][3], ab1, 0, 0, 0); \
    f32x4 t0 = (aa0 + ab0) * e2a;                                             \
    f32x4 t1 = (aa1 + ab1) * e2b;                                             \
    s0[rr] += t0[0] + t0[1] + t0[2] + t0[3];                                  \
    s1[rr] += t1[0] + t1[1] + t1[2] + t1[3];                                  \
} while (0)

// ---- main: 1024 threads / 16 waves, ALL of Cth in swizzled LDS ----
__global__ __launch_bounds__(1024) void bilinear_mfma_kernel(
    const float* __restrict__ e1g,           // [N, D]
    const float* __restrict__ e2g,           // [N, D]
    const unsigned short* __restrict__ Cth,  // [R, 128(e), 128(d)] bf16
    const int*   __restrict__ rels,
    float* __restrict__ out,                 // [1 + N]
    float* __restrict__ loss_ws,             // [NTILE2] per-wave loss partials
    float inv_n)
{
    __shared__ __align__(16) unsigned short s_c[81920];  // 160 KiB: all of Cth

    const int tid  = threadIdx.x;            // 0..1023
    const int lane = tid & 63;
    const int w    = tid >> 6;               // wave 0..15
    const int l15  = lane & 15;
    const int q    = lane >> 4;

    const int n0 = blockIdx.x * RPB + w * ROWS;
    const int na = n0 + l15;                 // row for tile nt=0
    const int nb = n0 + 16 + l15;            // row for tile nt=1

    // B-fragments from e1 (f32 -> bf16 in regs), pinned: 32 VGPR.
    bf16x8 bfr[2][4];
#pragma unroll
    for (int nt = 0; nt < 2; ++nt) {
        const float* p = e1g + (size_t)(n0 + 16 * nt + l15) * DDIM + q * 8;
#pragma unroll
        for (int k4 = 0; k4 < 4; ++k4) {
            float4 u0 = *(const float4*)(p + k4 * 32);
            float4 u1 = *(const float4*)(p + k4 * 32 + 4);
            union { ushort4 h[2]; bf16x8 v; } cv;
            cv.h[0] = f2bf4(u0);
            cv.h[1] = f2bf4(u1);
            bfr[nt][k4] = cv.v;
        }
    }

    const int rel0 = rels[na];
    const int rel1 = rels[nb];

    // ---- stage ALL of Cth -> LDS, XOR-swizzled ----
    // granule gi = 16B; A = gi*16; row bits (A>>8)&7 = e&7; swizzle bits 4-6.
#pragma unroll
    for (int j = 0; j < 10; ++j) {
        int gi = j * 1024 + tid;
        uint4 v = *(const uint4*)(Cth + gi * 8);
        int A  = gi * 16;
        int As = A ^ (((A >> 8) & 7) << 4);
        *(uint4*)((char*)s_c + As) = v;
    }

    __syncthreads();   // the ONLY block-wide barrier

    float s0[RCLS] = {0.f, 0.f, 0.f, 0.f, 0.f};
    float s1[RCLS] = {0.f, 0.f, 0.f, 0.f, 0.f};

    const int sw = (l15 & 7) << 4;                       // swizzle for reads
    const char* rowb = (const char*)s_c + l15 * 256;     // row e = et*16+l15
    const float* e2pa = e2g + (size_t)na * DDIM + q * 4;
    const float* e2pb = e2g + (size_t)nb * DDIM + q * 4;

    // e2 pipeline: load et=0 now; inside the loop issue et+1 before compute
    f32x4 e2a = *(const f32x4*)(e2pa);
    f32x4 e2b = *(const f32x4*)(e2pb);

#pragma unroll 1
    for (int et = 0; et < 8; ++et) {
        const char* rb = rowb + et * 4096;   // + et*16 rows * 256 B

        bf16x8 afA[4], afB[4];
        PREF(afA, 0);

        // issue next et's e2 (consumed one full iteration later)
        f32x4 e2an, e2bn;
        if (et < 7) {
            e2an = *(const f32x4*)(e2pa + (et + 1) * 16);
            e2bn = *(const f32x4*)(e2pb + (et + 1) * 16);
        }

        // software pipeline: reads for r+1 in flight during r's MFMAs
        PREF(afB, 1); COMP(afA, 0);
        PREF(afA, 2); COMP(afB, 1);
        PREF(afB, 3); COMP(afA, 2);
        PREF(afA, 4); COMP(afB, 3);
        COMP(afA, 4);

        e2a = e2an;
        e2b = e2bn;
    }

    // reduce over the 4 q-groups (e-span); all lanes end with full logits
#pragma unroll
    for (int r = 0; r < RCLS; ++r) {
        s0[r] += __shfl_xor(s0[r], 16); s0[r] += __shfl_xor(s0[r], 32);
        s1[r] += __shfl_xor(s1[r], 16); s1[r] += __shfl_xor(s1[r], 32);
    }

    // softmax epilogue (per lane, 2 rows); rel-gather via unrolled select
    float m0 = s0[0], m1 = s1[0];
#pragma unroll
    for (int r = 1; r < RCLS; ++r) { m0 = fmaxf(m0, s0[r]); m1 = fmaxf(m1, s1[r]); }
    float se0 = 0.f, pn0 = 0.f, lr0 = 0.f;
    float se1 = 0.f, pn1 = 0.f, lr1 = 0.f;
#pragma unroll
    for (int r = 0; r < RCLS; ++r) {
        float e0 = __expf(s0[r] - m0);
        float e1v = __expf(s1[r] - m1);
        se0 += e0;  pn0 += (float)(r + 1) * e0;
        se1 += e1v; pn1 += (float)(r + 1) * e1v;
        if (r == rel0) lr0 = s0[r];
        if (r == rel1) lr1 = s1[r];
    }
    if (q == 0) {
        out[1 + na] = pn0 / se0;
        out[1 + nb] = pn1 / se1;
    }
    float lossc = (q == 0)
        ? -((lr0 - m0 - logf(se0)) + (lr1 - m1 - logf(se1))) * inv_n
        : 0.f;
#pragma unroll
    for (int mm = 1; mm <= 32; mm <<= 1) lossc += __shfl_xor(lossc, mm);
    if (lane == 0) loss_ws[blockIdx.x * WAVES + w] = lossc;
}

// ---- final: reduce the per-wave partials into out[0] ----
__global__ __launch_bounds__(256) void loss_reduce_kernel(
    const float* __restrict__ loss_ws, float* __restrict__ out)
{
    __shared__ float s[4];
    float v = 0.0f;
    for (int i = threadIdx.x; i < NTILE2; i += 256) v += loss_ws[i];
#pragma unroll
    for (int m = 1; m <= 32; m <<= 1) v += __shfl_xor(v, m);
    if ((threadIdx.x & 63) == 0) s[threadIdx.x >> 6] = v;
    __syncthreads();
    if (threadIdx.x == 0) out[0] = s[0] + s[1] + s[2] + s[3];
}

extern "C" void kernel_launch(void* const* d_in, const int* in_sizes, int n_in,
                              void* d_out, int out_size, void* d_ws, size_t ws_size,
                              hipStream_t stream) {
    const float* e1   = (const float*)d_in[0];
    const float* e2   = (const float*)d_in[1];
    const float* rele = (const float*)d_in[2];
    const float* wsc  = (const float*)d_in[3];
    const int*   rels = (const int*)d_in[4];
    float* out = (float*)d_out;

    unsigned short* Cth = (unsigned short*)d_ws;             // 163840 B
    float* loss_ws = (float*)((char*)d_ws + 163840);         // 16384 B

    prep_kernel<<<80, 256, 0, stream>>>(rele, wsc, Cth);
    bilinear_mfma_kernel<<<GRID2, 1024, 0, stream>>>(
        e1, e2, Cth, rels, out, loss_ws, 1.0f / (float)NTOT);
    loss_reduce_kernel<<<1, 256, 0, stream>>>(loss_ws, out);
}